// Round 1
// baseline (67.891 us; speedup 1.0000x reference)
//
#include <hip/hip_runtime.h>

#define HDIM 1024
#define WDIM 1024
#define NPIX (HDIM*WDIM)
#define KDIM 5
#define KK 25
#define TX 32
#define TY 8

__global__ __launch_bounds__(256) void fused_step(
    const float* __restrict__ x,     // 6*N  [spike, V, R, A, T, E]
    const float* __restrict__ EI,    // N
    const float* __restrict__ nnk,   // 25*N
    const float* __restrict__ trm,   // N
    const float* __restrict__ ksI,   // N
    const float* __restrict__ ksE,   // N
    float* __restrict__ out)         // 32*N  [z(7N), new_k(25N)]
{
#pragma clang fp contract(off)
    __shared__ float s0t[TY + 4][TX + 4];
    __shared__ float at [TY + 4][TX + 4];

    const int bx  = blockIdx.x * TX;
    const int by  = blockIdx.y * TY;
    const int tid = threadIdx.y * TX + threadIdx.x;

    // cooperative halo-tile load with circular wrap (H=W=1024, pow2)
    for (int idx = tid; idx < (TY + 4) * (TX + 4); idx += TX * TY) {
        int r  = idx / (TX + 4);
        int c  = idx - r * (TX + 4);
        int gy = (by + r - 2) & (HDIM - 1);
        int gx = (bx + c - 2) & (WDIM - 1);
        int g  = gy * WDIM + gx;
        float sp = x[g];             // channel 0: spike
        float ei = EI[g];
        s0t[r][c] = sp * ei;         // S0 = spike * EI (one rounded mul)
        at [r][c] = x[3 * NPIX + g]; // channel 3: A (old)
    }
    __syncthreads();

    const int lx = threadIdx.x;
    const int ly = threadIdx.y;
    const int n  = (by + ly) * WDIM + (bx + lx);

    float nk[KK];
    #pragma unroll
    for (int kk = 0; kk < KK; ++kk) nk[kk] = nnk[kk * NPIX + n];

    // I = sum_{kk in order} S0[neighbor] * nk[kk]  (sequential, no fma)
    float I = 0.0f;
    #pragma unroll
    for (int i = 0; i < KDIM; ++i) {
        #pragma unroll
        for (int j = 0; j < KDIM; ++j) {
            float p = s0t[ly + i][lx + j] * nk[i * KDIM + j];
            I = I + p;
        }
    }

    float V  = x[1 * NPIX + n];
    float R  = x[2 * NPIX + n];
    float A  = at[ly + 2][lx + 2];
    float T  = x[4 * NPIX + n];
    float E  = x[5 * NPIX + n];
    float ei = EI[n];
    float tr = trm[n];

    // V = V - DECAY*V + INTEG*I, numpy order: (V - (0.2*V)) + (4*I)
    V = (V - 0.2f * V) + 4.0f * I;
    float S  = (V > T && R > 5.0f && E > 0.1f) ? 1.0f : 0.0f;
    float En = (E + 0.0058f * (1.0f - E)) - S * 0.1f;
    float Rn = (R + 1.0f) * (1.0f - S);
    float An = (A - A / 100.0f) + S;
    float Tn = (T - T / 1000.0f) + 0.05f * (An - tr);
    float Vo = V * (1.0f - S);

    float ei_neg = (ei < 0.0f) ? 1.0f : 0.0f;
    float fac    = An - tr * ei_neg;   // post - trm*ei_neg

    float colsum = 0.0f;
    #pragma unroll
    for (int i = 0; i < KDIM; ++i) {
        #pragma unroll
        for (int j = 0; j < KDIM; ++j) {
            int   kk  = i * KDIM + j;
            float pre = at[ly + i][lx + j];
            float d   = (nk[kk] > 1e-6f) ? pre * fac : 0.0f;
            float v   = nk[kk] + 0.01f * d;
            v = fmaxf(v, 0.0f);
            if (kk == 12) v = 0.0f;   // center zeroed before normalization
            nk[kk] = v;
            colsum += v;
        }
    }

    float ks    = (ei < 0.0f) ? ksI[n] : ksE[n];
    float scale = ks / (colsum + 1e-6f);

    out[0 * NPIX + n] = S;
    out[1 * NPIX + n] = Vo;
    out[2 * NPIX + n] = Rn;
    out[3 * NPIX + n] = An;
    out[4 * NPIX + n] = Tn;
    out[5 * NPIX + n] = En;
    out[6 * NPIX + n] = ei;

    #pragma unroll
    for (int kk = 0; kk < KK; ++kk)
        out[7 * NPIX + kk * NPIX + n] = nk[kk] * scale;
}

extern "C" void kernel_launch(void* const* d_in, const int* in_sizes, int n_in,
                              void* d_out, int out_size, void* d_ws, size_t ws_size,
                              hipStream_t stream) {
    const float* x    = (const float*)d_in[0];
    // d_in[1] = noise_input (unused by reference)
    const float* EI   = (const float*)d_in[2];
    const float* nnk  = (const float*)d_in[3];
    const float* trm  = (const float*)d_in[4];
    // d_in[5] = if_inhib (bool; recomputed as EI<0, exact)
    const float* ksI  = (const float*)d_in[6];
    const float* ksE  = (const float*)d_in[7];
    float* out = (float*)d_out;

    dim3 block(TX, TY);
    dim3 grid(WDIM / TX, HDIM / TY);
    fused_step<<<grid, block, 0, stream>>>(x, EI, nnk, trm, ksI, ksE, out);
}

// Round 2
// 57.561 us; speedup vs baseline: 1.1795x; 1.1795x over previous
//
#include <hip/hip_runtime.h>

#define HDIM 1024
#define WDIM 1024
#define NPIX (HDIM*WDIM)
#define KDIM 5
#define KK 25
#define TX 32
#define TY 8
#define PXT 4                  // pixels per thread (float4 path)
#define TILEW (TX*PXT)         // 128
#define HALOW (TILEW + 4)      // 132 valid cols
#define TCOLS (TILEW + 8)      // 136 padded row stride (16B multiple)
#define TROWS (TY + 4)         // 12

typedef float f4 __attribute__((ext_vector_type(4)));

__global__ __launch_bounds__(256) void fused_step(
    const float* __restrict__ x,     // 6*N  [spike, V, R, A, T, E]
    const float* __restrict__ EI,    // N
    const float* __restrict__ nnk,   // 25*N
    const float* __restrict__ trm,   // N
    const float* __restrict__ ksI,   // N
    const float* __restrict__ ksE,   // N
    float* __restrict__ out)         // 32*N  [z(7N), new_k(25N)]
{
#pragma clang fp contract(off)
    __shared__ __align__(16) float s0t[TROWS][TCOLS];
    __shared__ __align__(16) float at [TROWS][TCOLS];

    const int bx  = blockIdx.x * TILEW;
    const int by  = blockIdx.y * TY;
    const int tid = threadIdx.y * TX + threadIdx.x;

    // cooperative halo-tile load with circular wrap (H=W=1024, pow2)
    for (int idx = tid; idx < TROWS * HALOW; idx += TX * TY) {
        int r  = idx / HALOW;
        int c  = idx - r * HALOW;
        int gy = (by + r - 2) & (HDIM - 1);
        int gx = (bx + c - 2) & (WDIM - 1);
        int g  = gy * WDIM + gx;
        s0t[r][c] = x[g] * EI[g];     // S0 = spike * EI
        at [r][c] = x[3 * NPIX + g];  // old A
    }
    __syncthreads();

    const int lx = threadIdx.x;
    const int ly = threadIdx.y;
    const int n  = (by + ly) * WDIM + bx + lx * PXT;   // 16B-aligned base pixel

    f4 nk[KK];
    #pragma unroll
    for (int kk = 0; kk < KK; ++kk)
        nk[kk] = *reinterpret_cast<const f4*>(&nnk[kk * NPIX + n]);

    // I[q] = sum_{kk in order} S0[nbr] * nk[kk][q], sequential, no fma
    f4 I = {0.0f, 0.0f, 0.0f, 0.0f};
    #pragma unroll
    for (int i = 0; i < KDIM; ++i) {
        const float* row = &s0t[ly + i][lx * PXT];
        f4 a = *reinterpret_cast<const f4*>(row);
        f4 b = *reinterpret_cast<const f4*>(row + 4);
        float e[8] = {a[0], a[1], a[2], a[3], b[0], b[1], b[2], b[3]};
        #pragma unroll
        for (int j = 0; j < KDIM; ++j) {
            const int kk = i * KDIM + j;
            #pragma unroll
            for (int q = 0; q < PXT; ++q) {
                float p = e[q + j] * nk[kk][q];
                I[q] = I[q] + p;
            }
        }
    }

    f4 V  = *reinterpret_cast<const f4*>(&x[1 * NPIX + n]);
    f4 R  = *reinterpret_cast<const f4*>(&x[2 * NPIX + n]);
    f4 A  = *reinterpret_cast<const f4*>(&x[3 * NPIX + n]);
    f4 T  = *reinterpret_cast<const f4*>(&x[4 * NPIX + n]);
    f4 E  = *reinterpret_cast<const f4*>(&x[5 * NPIX + n]);
    f4 ei = *reinterpret_cast<const f4*>(&EI[n]);
    f4 tr = *reinterpret_cast<const f4*>(&trm[n]);
    f4 kI = *reinterpret_cast<const f4*>(&ksI[n]);
    f4 kE = *reinterpret_cast<const f4*>(&ksE[n]);

    f4 S, Vo, Rn, An, Tn, En, fac;
    #pragma unroll
    for (int q = 0; q < PXT; ++q) {
        float v = (V[q] - 0.2f * V[q]) + 4.0f * I[q];
        float s = (v > T[q] && R[q] > 5.0f && E[q] > 0.1f) ? 1.0f : 0.0f;
        En[q] = (E[q] + 0.0058f * (1.0f - E[q])) - s * 0.1f;
        Rn[q] = (R[q] + 1.0f) * (1.0f - s);
        float an = (A[q] - A[q] / 100.0f) + s;
        An[q] = an;
        Tn[q] = (T[q] - T[q] / 1000.0f) + 0.05f * (an - tr[q]);
        Vo[q] = v * (1.0f - s);
        S[q]  = s;
        float ei_neg = (ei[q] < 0.0f) ? 1.0f : 0.0f;
        fac[q] = an - tr[q] * ei_neg;
    }

    // Hebbian update + column sum
    f4 colsum = {0.0f, 0.0f, 0.0f, 0.0f};
    #pragma unroll
    for (int i = 0; i < KDIM; ++i) {
        const float* row = &at[ly + i][lx * PXT];
        f4 a = *reinterpret_cast<const f4*>(row);
        f4 b = *reinterpret_cast<const f4*>(row + 4);
        float e[8] = {a[0], a[1], a[2], a[3], b[0], b[1], b[2], b[3]};
        #pragma unroll
        for (int j = 0; j < KDIM; ++j) {
            const int kk = i * KDIM + j;
            #pragma unroll
            for (int q = 0; q < PXT; ++q) {
                float d = (nk[kk][q] > 1e-6f) ? e[q + j] * fac[q] : 0.0f;
                float v = nk[kk][q] + 0.01f * d;
                v = fmaxf(v, 0.0f);
                if (kk == KK / 2) v = 0.0f;   // center zeroed pre-normalization
                nk[kk][q] = v;
                colsum[q] += v;
            }
        }
    }

    f4 scale;
    #pragma unroll
    for (int q = 0; q < PXT; ++q) {
        float ks = (ei[q] < 0.0f) ? kI[q] : kE[q];
        scale[q] = ks / (colsum[q] + 1e-6f);
    }

    *reinterpret_cast<f4*>(&out[0 * NPIX + n]) = S;
    *reinterpret_cast<f4*>(&out[1 * NPIX + n]) = Vo;
    *reinterpret_cast<f4*>(&out[2 * NPIX + n]) = Rn;
    *reinterpret_cast<f4*>(&out[3 * NPIX + n]) = An;
    *reinterpret_cast<f4*>(&out[4 * NPIX + n]) = Tn;
    *reinterpret_cast<f4*>(&out[5 * NPIX + n]) = En;
    *reinterpret_cast<f4*>(&out[6 * NPIX + n]) = ei;

    #pragma unroll
    for (int kk = 0; kk < KK; ++kk) {
        f4 v;
        #pragma unroll
        for (int q = 0; q < PXT; ++q) v[q] = nk[kk][q] * scale[q];
        *reinterpret_cast<f4*>(&out[7 * NPIX + kk * NPIX + n]) = v;
    }
}

extern "C" void kernel_launch(void* const* d_in, const int* in_sizes, int n_in,
                              void* d_out, int out_size, void* d_ws, size_t ws_size,
                              hipStream_t stream) {
    const float* x    = (const float*)d_in[0];
    const float* EI   = (const float*)d_in[2];
    const float* nnk  = (const float*)d_in[3];
    const float* trm  = (const float*)d_in[4];
    const float* ksI  = (const float*)d_in[6];
    const float* ksE  = (const float*)d_in[7];
    float* out = (float*)d_out;

    dim3 block(TX, TY);
    dim3 grid(WDIM / TILEW, HDIM / TY);
    fused_step<<<grid, block, 0, stream>>>(x, EI, nnk, trm, ksI, ksE, out);
}

// Round 3
// 50.539 us; speedup vs baseline: 1.3433x; 1.1389x over previous
//
#include <hip/hip_runtime.h>

#define HDIM 1024
#define WDIM 1024
#define NPIX (HDIM*WDIM)
#define KDIM 5
#define KK 25
#define TX 32
#define TY 8
#define PXT 4                  // pixels per thread (float4 path)
#define TILEW (TX*PXT)         // 128
#define HALOW (TILEW + 4)      // 132 valid cols
#define TCOLS (TILEW + 8)      // 136 padded row stride (16B multiple)
#define TROWS (TY + 4)         // 12

typedef float f4 __attribute__((ext_vector_type(4)));

__global__ __launch_bounds__(256) void fused_step(
    const float* __restrict__ x,     // 6*N  [spike, V, R, A, T, E]
    const float* __restrict__ EI,    // N
    const float* __restrict__ nnk,   // 25*N
    const float* __restrict__ trm,   // N
    const float* __restrict__ ksI,   // N
    const float* __restrict__ ksE,   // N
    float* __restrict__ out)         // 32*N  [z(7N), new_k(25N)]
{
#pragma clang fp contract(off)
    __shared__ __align__(16) float s0t[TROWS][TCOLS];
    __shared__ __align__(16) float at [TROWS][TCOLS];

    const int bx  = blockIdx.x * TILEW;
    const int by  = blockIdx.y * TY;
    const int tid = threadIdx.y * TX + threadIdx.x;
    const int lx  = threadIdx.x;
    const int ly  = threadIdx.y;
    const int n   = (by + ly) * WDIM + bx + lx * PXT;  // 16B-aligned base pixel

    // Issue the 25 nn_k vector loads FIRST so they fly concurrently with the
    // halo staging loads below (vmcnt queue shared; all overlap until barrier).
    f4 nk[KK];
    #pragma unroll
    for (int kk = 0; kk < KK; ++kk)
        nk[kk] = *reinterpret_cast<const f4*>(&nnk[kk * NPIX + n]);

    // cooperative halo-tile load with circular wrap (H=W=1024, pow2)
    for (int idx = tid; idx < TROWS * HALOW; idx += TX * TY) {
        int r  = idx / HALOW;
        int c  = idx - r * HALOW;
        int gy = (by + r - 2) & (HDIM - 1);
        int gx = (bx + c - 2) & (WDIM - 1);
        int g  = gy * WDIM + gx;
        s0t[r][c] = x[g] * EI[g];     // S0 = spike * EI
        at [r][c] = x[3 * NPIX + g];  // old A
    }
    __syncthreads();

    // I[q] = sum_{kk in order} S0[nbr] * nk[kk][q], sequential, no fma
    f4 I = {0.0f, 0.0f, 0.0f, 0.0f};
    #pragma unroll
    for (int i = 0; i < KDIM; ++i) {
        const float* row = &s0t[ly + i][lx * PXT];
        f4 a = *reinterpret_cast<const f4*>(row);
        f4 b = *reinterpret_cast<const f4*>(row + 4);
        float e[8] = {a[0], a[1], a[2], a[3], b[0], b[1], b[2], b[3]};
        #pragma unroll
        for (int j = 0; j < KDIM; ++j) {
            const int kk = i * KDIM + j;
            #pragma unroll
            for (int q = 0; q < PXT; ++q) {
                float p = e[q + j] * nk[kk][q];
                I[q] = I[q] + p;
            }
        }
    }

    f4 V  = *reinterpret_cast<const f4*>(&x[1 * NPIX + n]);
    f4 R  = *reinterpret_cast<const f4*>(&x[2 * NPIX + n]);
    f4 A  = *reinterpret_cast<const f4*>(&x[3 * NPIX + n]);
    f4 T  = *reinterpret_cast<const f4*>(&x[4 * NPIX + n]);
    f4 E  = *reinterpret_cast<const f4*>(&x[5 * NPIX + n]);
    f4 ei = *reinterpret_cast<const f4*>(&EI[n]);
    f4 tr = *reinterpret_cast<const f4*>(&trm[n]);
    f4 kI = *reinterpret_cast<const f4*>(&ksI[n]);
    f4 kE = *reinterpret_cast<const f4*>(&ksE[n]);

    f4 S, Vo, Rn, An, Tn, En, fac;
    #pragma unroll
    for (int q = 0; q < PXT; ++q) {
        float v = (V[q] - 0.2f * V[q]) + 4.0f * I[q];
        float s = (v > T[q] && R[q] > 5.0f && E[q] > 0.1f) ? 1.0f : 0.0f;
        En[q] = (E[q] + 0.0058f * (1.0f - E[q])) - s * 0.1f;
        Rn[q] = (R[q] + 1.0f) * (1.0f - s);
        float an = (A[q] - A[q] / 100.0f) + s;
        An[q] = an;
        Tn[q] = (T[q] - T[q] / 1000.0f) + 0.05f * (an - tr[q]);
        Vo[q] = v * (1.0f - s);
        S[q]  = s;
        float ei_neg = (ei[q] < 0.0f) ? 1.0f : 0.0f;
        fac[q] = an - tr[q] * ei_neg;
    }

    // Hebbian update + column sum
    f4 colsum = {0.0f, 0.0f, 0.0f, 0.0f};
    #pragma unroll
    for (int i = 0; i < KDIM; ++i) {
        const float* row = &at[ly + i][lx * PXT];
        f4 a = *reinterpret_cast<const f4*>(row);
        f4 b = *reinterpret_cast<const f4*>(row + 4);
        float e[8] = {a[0], a[1], a[2], a[3], b[0], b[1], b[2], b[3]};
        #pragma unroll
        for (int j = 0; j < KDIM; ++j) {
            const int kk = i * KDIM + j;
            #pragma unroll
            for (int q = 0; q < PXT; ++q) {
                float d = (nk[kk][q] > 1e-6f) ? e[q + j] * fac[q] : 0.0f;
                float v = nk[kk][q] + 0.01f * d;
                v = fmaxf(v, 0.0f);
                if (kk == KK / 2) v = 0.0f;   // center zeroed pre-normalization
                nk[kk][q] = v;
                colsum[q] += v;
            }
        }
    }

    f4 scale;
    #pragma unroll
    for (int q = 0; q < PXT; ++q) {
        float ks = (ei[q] < 0.0f) ? kI[q] : kE[q];
        scale[q] = ks / (colsum[q] + 1e-6f);
    }

    // Non-temporal stores: outputs are write-once/never-read — keep them from
    // evicting the (L3-resident, 144MB) input set.
    __builtin_nontemporal_store(S,  reinterpret_cast<f4*>(&out[0 * NPIX + n]));
    __builtin_nontemporal_store(Vo, reinterpret_cast<f4*>(&out[1 * NPIX + n]));
    __builtin_nontemporal_store(Rn, reinterpret_cast<f4*>(&out[2 * NPIX + n]));
    __builtin_nontemporal_store(An, reinterpret_cast<f4*>(&out[3 * NPIX + n]));
    __builtin_nontemporal_store(Tn, reinterpret_cast<f4*>(&out[4 * NPIX + n]));
    __builtin_nontemporal_store(En, reinterpret_cast<f4*>(&out[5 * NPIX + n]));
    __builtin_nontemporal_store(ei, reinterpret_cast<f4*>(&out[6 * NPIX + n]));

    #pragma unroll
    for (int kk = 0; kk < KK; ++kk) {
        f4 v;
        #pragma unroll
        for (int q = 0; q < PXT; ++q) v[q] = nk[kk][q] * scale[q];
        __builtin_nontemporal_store(v, reinterpret_cast<f4*>(&out[7 * NPIX + kk * NPIX + n]));
    }
}

extern "C" void kernel_launch(void* const* d_in, const int* in_sizes, int n_in,
                              void* d_out, int out_size, void* d_ws, size_t ws_size,
                              hipStream_t stream) {
    const float* x    = (const float*)d_in[0];
    const float* EI   = (const float*)d_in[2];
    const float* nnk  = (const float*)d_in[3];
    const float* trm  = (const float*)d_in[4];
    const float* ksI  = (const float*)d_in[6];
    const float* ksE  = (const float*)d_in[7];
    float* out = (float*)d_out;

    dim3 block(TX, TY);
    dim3 grid(WDIM / TILEW, HDIM / TY);
    fused_step<<<grid, block, 0, stream>>>(x, EI, nnk, trm, ksI, ksE, out);
}